// Round 7
// baseline (154.087 us; speedup 1.0000x reference)
//
#include <hip/hip_runtime.h>
#include <math.h>

// Problem constants (from the JAX reference)
#define IMG    14
#define HW     196       // 14*14 spatial positions
#define DEPTH  512       // channels C
#define NB     512       // batch
#define NQ     4         // spatial segments per image
#define PS     49        // positions per thread (196 / 4)
#define NG     128       // f32x4 channel groups per image (512 / 4)

typedef float f32x4 __attribute__((ext_vector_type(4)));
typedef int   i32x4 __attribute__((ext_vector_type(4)));

// One block = one batch image (dense 401 KB footprint). Block: 512 threads =
// 8 waves. Thread (g = tid&127: f32x4 channel group, q = tid>>7: 49
// consecutive positions). Wave access = 1 KB contiguous; block union is a
// dense linear 401 KB region -> dense HBM streams (vs the 256B@2048B strided
// streams of rounds 1-6 that capped at ~2.5 TB/s). Argmax closes in-block via
// a 16 KB LDS partial array. Phase 2 re-reads (L3-resident: all 512 blocks'
// phase-1 loads the whole 196 MB input into the 256 MB L3), masks, stores.
__global__ __launch_bounds__(512, 8) void mask_kernel(const float* __restrict__ x,
                                                      float* __restrict__ out) {
    const int tid = threadIdx.x;
    const int g   = tid & (NG - 1);   // channel group 0..127
    const int q   = tid >> 7;         // spatial segment 0..3
    const int b   = blockIdx.x;
    const int c0  = g << 2;

    const size_t base = ((size_t)b * HW + (size_t)q * PS) * DEPTH + (size_t)c0;
    const float* px = x + base;
    float*       po = out + base;

    // ---- Phase 1: 49 dense dwordx4 loads, streaming per-component argmax ----
    float b0 = -INFINITY, b1 = -INFINITY, b2 = -INFINITY, b3 = -INFINITY;
    int   i0 = 0, i1 = 0, i2 = 0, i3 = 0;
#pragma unroll
    for (int k = 0; k < PS; ++k) {
        const f32x4 v = *(const f32x4*)(px + (size_t)k * DEPTH);
        const int s = q * PS + k;
        if (v.x > b0) { b0 = v.x; i0 = s; }
        if (v.y > b1) { b1 = v.y; i1 = s; }
        if (v.z > b2) { b2 = v.z; i2 = s; }
        if (v.w > b3) { b3 = v.w; i3 = s; }
    }

    // ---- Cross-segment argmax via LDS partials (16 KB) ----
    __shared__ f32x4 pmax[NQ][NG];
    __shared__ i32x4 pidx[NQ][NG];
    pmax[q][g] = (f32x4){b0, b1, b2, b3};
    pidx[q][g] = (i32x4){i0, i1, i2, i3};
    __syncthreads();

    f32x4 mv = pmax[0][g];
    i32x4 mi = pidx[0][g];
#pragma unroll
    for (int r = 1; r < NQ; ++r) {
        // (val >, or == with smaller idx) merge == first occurrence, matching
        // jnp.argmax tie semantics regardless of merge order
        const f32x4 vv = pmax[r][g];
        const i32x4 ii = pidx[r][g];
        if (vv.x > mv.x || (vv.x == mv.x && ii.x < mi.x)) { mv.x = vv.x; mi.x = ii.x; }
        if (vv.y > mv.y || (vv.y == mv.y && ii.y < mi.y)) { mv.y = vv.y; mi.y = ii.y; }
        if (vv.z > mv.z || (vv.z == mv.z && ii.z < mi.z)) { mv.z = vv.z; mi.z = ii.z; }
        if (vv.w > mv.w || (vv.w == mv.w && ii.w < mi.w)) { mv.w = vv.w; mi.w = ii.w; }
    }

    const float fi0 = (float)(mi.x / IMG), fj0 = (float)(mi.x % IMG);
    const float fi1 = (float)(mi.y / IMG), fj1 = (float)(mi.y % IMG);
    const float fi2 = (float)(mi.z / IMG), fj2 = (float)(mi.z % IMG);
    const float fi3 = (float)(mi.w / IMG), fj3 = (float)(mi.w % IMG);
    const float TAU = (float)(0.5 / 196.0);

    // s0 = 49q:  si0 = 7*(q>>1) + 3*(q&1), sj0 = 7*(q&1)   (exact)
    int si = 7 * (q >> 1) + 3 * (q & 1);
    int sj = 7 * (q & 1);

    // ---- Phase 2: dense re-read (L3-hot), mask, dense store ----
#pragma unroll
    for (int k = 0; k < PS; ++k) {
        const f32x4 v = *(const f32x4*)(px + (size_t)k * DEPTH);
        const float fsi = (float)si;
        const float fsj = (float)sj;
        f32x4 o;
        {
            const float dist = fabsf(fsi - fi0) + fabsf(fsj - fj0);
            o.x = v.x * (TAU * fmaxf(1.0f - (4.0f * dist) / 14.0f, -1.0f));
        }
        {
            const float dist = fabsf(fsi - fi1) + fabsf(fsj - fj1);
            o.y = v.y * (TAU * fmaxf(1.0f - (4.0f * dist) / 14.0f, -1.0f));
        }
        {
            const float dist = fabsf(fsi - fi2) + fabsf(fsj - fj2);
            o.z = v.z * (TAU * fmaxf(1.0f - (4.0f * dist) / 14.0f, -1.0f));
        }
        {
            const float dist = fabsf(fsi - fi3) + fabsf(fsj - fj3);
            o.w = v.w * (TAU * fmaxf(1.0f - (4.0f * dist) / 14.0f, -1.0f));
        }
        *(f32x4*)(po + (size_t)k * DEPTH) = o;
        ++sj;
        if (sj == IMG) { sj = 0; ++si; }
    }
}

extern "C" void kernel_launch(void* const* d_in, const int* in_sizes, int n_in,
                              void* d_out, int out_size, void* d_ws, size_t ws_size,
                              hipStream_t stream) {
    (void)in_sizes; (void)n_in; (void)out_size; (void)d_ws; (void)ws_size;
    const float* x = (const float*)d_in[0];
    float* out = (float*)d_out;
    dim3 grid(NB);       // 512 blocks, one per batch image
    dim3 block(512);
    hipLaunchKernelGGL(mask_kernel, grid, block, 0, stream, x, out);
}

// Round 8
// 139.859 us; speedup vs baseline: 1.1017x; 1.1017x over previous
//
#include <hip/hip_runtime.h>
#include <math.h>

// Problem constants (from the JAX reference)
#define IMG    14
#define HW     196       // 14*14 spatial positions
#define DEPTH  512       // channels C
#define NB     512       // batch
#define NQ     4         // s-phase groups (tid>>7)
#define MPT    49        // chunks (steps) per thread
#define NG     128       // f32x4 channel groups per position (512/4)
#define BLK    512

typedef float f32x4 __attribute__((ext_vector_type(4)));
typedef int   i32x4 __attribute__((ext_vector_type(4)));

// One block = one batch image (401 KB). Linear mapping: image chunk index
// (f32x4 granularity) = tid + 512*m, m = 0..48. chunk&127 = tid&127, so each
// thread owns a FIXED 4-channel group (cg) and visits s = (tid>>7) + 4m
// (ascending). At each step m the whole block touches chunks [512m, 512m+512)
// = 8 KB CONTIGUOUS -> the block walks its image as one linear stream (vs
// R7's 4-way-interleaved strided walk). Argmax closes in-block via 16 KB LDS
// partials with idx-min tie-break (exact first-occurrence). Phase 2 re-reads
// the same linear chunks (L3-hot), masks, stores linearly.
__global__ __launch_bounds__(BLK, 8) void mask_kernel(const float* __restrict__ x,
                                                      float* __restrict__ out) {
    const int tid = threadIdx.x;
    const int cg  = tid & (NG - 1);   // fixed f32x4 channel group 0..127
    const int q   = tid >> 7;         // s-phase 0..3  (s = q + 4m)
    const int b   = blockIdx.x;

    const f32x4* px = (const f32x4*)(x   + (size_t)b * HW * DEPTH);
    f32x4*       po = (f32x4*)      (out + (size_t)b * HW * DEPTH);

    // ---- Phase 1: linear read, streaming per-component argmax ----
    float b0 = -INFINITY, b1 = -INFINITY, b2 = -INFINITY, b3 = -INFINITY;
    int   i0 = 0, i1 = 0, i2 = 0, i3 = 0;
#pragma unroll
    for (int m = 0; m < MPT; ++m) {
        const f32x4 v = px[tid + BLK * m];
        const int s = q + 4 * m;      // ascending -> strict > = first occurrence
        if (v.x > b0) { b0 = v.x; i0 = s; }
        if (v.y > b1) { b1 = v.y; i1 = s; }
        if (v.z > b2) { b2 = v.z; i2 = s; }
        if (v.w > b3) { b3 = v.w; i3 = s; }
    }

    // ---- Cross-phase argmax via LDS partials (16 KB) ----
    __shared__ f32x4 pmax[NQ][NG];
    __shared__ i32x4 pidx[NQ][NG];
    pmax[q][cg] = (f32x4){b0, b1, b2, b3};
    pidx[q][cg] = (i32x4){i0, i1, i2, i3};
    __syncthreads();

    f32x4 mv = pmax[0][cg];
    i32x4 mi = pidx[0][cg];
#pragma unroll
    for (int r = 1; r < NQ; ++r) {
        // (val >, or == with smaller idx) merge == first occurrence, matching
        // jnp.argmax tie semantics regardless of merge order
        const f32x4 vv = pmax[r][cg];
        const i32x4 ii = pidx[r][cg];
        if (vv.x > mv.x || (vv.x == mv.x && ii.x < mi.x)) { mv.x = vv.x; mi.x = ii.x; }
        if (vv.y > mv.y || (vv.y == mv.y && ii.y < mi.y)) { mv.y = vv.y; mi.y = ii.y; }
        if (vv.z > mv.z || (vv.z == mv.z && ii.z < mi.z)) { mv.z = vv.z; mi.z = ii.z; }
        if (vv.w > mv.w || (vv.w == mv.w && ii.w < mi.w)) { mv.w = vv.w; mi.w = ii.w; }
    }

    const float fi0 = (float)(mi.x / IMG), fj0 = (float)(mi.x % IMG);
    const float fi1 = (float)(mi.y / IMG), fj1 = (float)(mi.y % IMG);
    const float fi2 = (float)(mi.z / IMG), fj2 = (float)(mi.z % IMG);
    const float fi3 = (float)(mi.w / IMG), fj3 = (float)(mi.w % IMG);
    const float TAU = (float)(0.5 / 196.0);

    // ---- Phase 2: linear re-read (L3-hot), mask, linear store ----
    // s = q + 4m: starts at (si=0, sj=q); step +4 wraps at most once per step
    int si = 0, sj = q;
#pragma unroll
    for (int m = 0; m < MPT; ++m) {
        const f32x4 v = px[tid + BLK * m];
        const float fsi = (float)si;
        const float fsj = (float)sj;
        f32x4 o;
        {
            const float dist = fabsf(fsi - fi0) + fabsf(fsj - fj0);
            o.x = v.x * (TAU * fmaxf(1.0f - (4.0f * dist) / 14.0f, -1.0f));
        }
        {
            const float dist = fabsf(fsi - fi1) + fabsf(fsj - fj1);
            o.y = v.y * (TAU * fmaxf(1.0f - (4.0f * dist) / 14.0f, -1.0f));
        }
        {
            const float dist = fabsf(fsi - fi2) + fabsf(fsj - fj2);
            o.z = v.z * (TAU * fmaxf(1.0f - (4.0f * dist) / 14.0f, -1.0f));
        }
        {
            const float dist = fabsf(fsi - fi3) + fabsf(fsj - fj3);
            o.w = v.w * (TAU * fmaxf(1.0f - (4.0f * dist) / 14.0f, -1.0f));
        }
        po[tid + BLK * m] = o;
        sj += 4;
        if (sj >= IMG) { sj -= IMG; ++si; }
    }
}

extern "C" void kernel_launch(void* const* d_in, const int* in_sizes, int n_in,
                              void* d_out, int out_size, void* d_ws, size_t ws_size,
                              hipStream_t stream) {
    (void)in_sizes; (void)n_in; (void)out_size; (void)d_ws; (void)ws_size;
    const float* x = (const float*)d_in[0];
    float* out = (float*)d_out;
    dim3 grid(NB);       // 512 blocks, one per batch image
    dim3 block(BLK);
    hipLaunchKernelGGL(mask_kernel, grid, block, 0, stream, x, out);
}

// Round 9
// 100.240 us; speedup vs baseline: 1.5372x; 1.3952x over previous
//
#include <hip/hip_runtime.h>
#include <math.h>

// Problem constants (from the JAX reference)
#define IMG    14
#define HW     196       // 14*14 spatial positions
#define DEPTH  512       // channels C
#define NB     512       // batch
#define RPT    7         // spatial rows per thread (196 / 28)
#define GPR    16        // f32x4 channel groups per block tile
#define CTILE  64        // channels per block
#define NWAVE  7
#define BLK    448

typedef float f32x4 __attribute__((ext_vector_type(4)));
typedef int   i32x4 __attribute__((ext_vector_type(4)));

// Block: 448 threads = 7 waves. Thread (g = tid&15, q = tid>>4): one f32x4
// channel group x 7 consecutive spatial positions (dwordx4 loads/stores).
// VALU diet vs rounds 1-8: (a) mask uses fmaf(dist,-C,1) instead of the fp32
// division (4*dist)/14.0f -- the division emitted a ~9-inst v_div sequence
// x4 components x every chunk, ~35 VALU insts/16B; (b) argmax merge is a
// 2-step shfl_xor butterfly + 7-partial LDS merge (3.5 KB) instead of a
// 28-way merge loop. Grid: 512 b x 8 ctiles = 4096 blocks.
__global__ __launch_bounds__(BLK) void mask_kernel(const float* __restrict__ x,
                                                   float* __restrict__ out) {
    const int tid = threadIdx.x;
    const int g   = tid & 15;      // channel group
    const int q   = tid >> 4;      // spatial segment 0..27
    const int w   = tid >> 6;      // wave 0..6
    const int b   = blockIdx.x >> 3;
    const int ct  = blockIdx.x & 7;
    const int c0  = ct * CTILE + (g << 2);

    const size_t base = ((size_t)b * HW + (size_t)q * RPT) * DEPTH + (size_t)c0;
    const float* px = x + base;
    float*       po = out + base;

    // ---- Phase 1: 7 dwordx4 loads, streaming per-component argmax ----
    float b0 = -INFINITY, b1 = -INFINITY, b2 = -INFINITY, b3 = -INFINITY;
    int   i0 = 0, i1 = 0, i2 = 0, i3 = 0;
#pragma unroll
    for (int k = 0; k < RPT; ++k) {
        const f32x4 v = *(const f32x4*)(px + (size_t)k * DEPTH);
        const int s = q * RPT + k;   // ascending: strict > = first occurrence
        if (v.x > b0) { b0 = v.x; i0 = s; }
        if (v.y > b1) { b1 = v.y; i1 = s; }
        if (v.z > b2) { b2 = v.z; i2 = s; }
        if (v.w > b3) { b3 = v.w; i3 = s; }
    }

    // ---- Intra-wave butterfly: lanes {l, l^16, l^32, l^48} share g ----
    // (val >, or == with smaller idx) merge == first occurrence, matching
    // jnp.argmax tie semantics regardless of merge order.
#pragma unroll
    for (int m = 16; m <= 32; m <<= 1) {
        const float o0 = __shfl_xor(b0, m); const int oi0 = __shfl_xor(i0, m);
        const float o1 = __shfl_xor(b1, m); const int oi1 = __shfl_xor(i1, m);
        const float o2 = __shfl_xor(b2, m); const int oi2 = __shfl_xor(i2, m);
        const float o3 = __shfl_xor(b3, m); const int oi3 = __shfl_xor(i3, m);
        if (o0 > b0 || (o0 == b0 && oi0 < i0)) { b0 = o0; i0 = oi0; }
        if (o1 > b1 || (o1 == b1 && oi1 < i1)) { b1 = o1; i1 = oi1; }
        if (o2 > b2 || (o2 == b2 && oi2 < i2)) { b2 = o2; i2 = oi2; }
        if (o3 > b3 || (o3 == b3 && oi3 < i3)) { b3 = o3; i3 = oi3; }
    }

    // ---- Cross-wave merge via tiny LDS partial array (3.5 KB) ----
    __shared__ f32x4 pmax[NWAVE][GPR];
    __shared__ i32x4 pidx[NWAVE][GPR];
    if ((tid & 63) < 16) {
        pmax[w][g] = (f32x4){b0, b1, b2, b3};
        pidx[w][g] = (i32x4){i0, i1, i2, i3};
    }
    __syncthreads();

    f32x4 mv = pmax[0][g];
    i32x4 mi = pidx[0][g];
#pragma unroll
    for (int r = 1; r < NWAVE; ++r) {
        const f32x4 vv = pmax[r][g];
        const i32x4 ii = pidx[r][g];
        if (vv.x > mv.x || (vv.x == mv.x && ii.x < mi.x)) { mv.x = vv.x; mi.x = ii.x; }
        if (vv.y > mv.y || (vv.y == mv.y && ii.y < mi.y)) { mv.y = vv.y; mi.y = ii.y; }
        if (vv.z > mv.z || (vv.z == mv.z && ii.z < mi.z)) { mv.z = vv.z; mi.z = ii.z; }
        if (vv.w > mv.w || (vv.w == mv.w && ii.w < mi.w)) { mv.w = vv.w; mi.w = ii.w; }
    }

    const float fi0 = (float)(mi.x / IMG), fj0 = (float)(mi.x % IMG);
    const float fi1 = (float)(mi.y / IMG), fj1 = (float)(mi.y % IMG);
    const float fi2 = (float)(mi.z / IMG), fj2 = (float)(mi.z % IMG);
    const float fi3 = (float)(mi.w / IMG), fj3 = (float)(mi.w % IMG);
    const float TAU = (float)(0.5 / 196.0);
    const float nC  = -(float)(4.0 / 14.0);   // -BETA/n; fma replaces fp32 div

    // ---- Phase 2: re-read (L2/L3-hot), division-free mask, store ----
#pragma unroll
    for (int k = 0; k < RPT; ++k) {
        const f32x4 v = *(const f32x4*)(px + (size_t)k * DEPTH);
        const int s = q * RPT + k;                 // compile-time per k
        const float fsi = (float)(s / IMG);
        const float fsj = (float)(s % IMG);
        f32x4 o;
        {
            const float d = fabsf(fsi - fi0) + fabsf(fsj - fj0);
            o.x = v.x * (TAU * fmaxf(fmaf(d, nC, 1.0f), -1.0f));
        }
        {
            const float d = fabsf(fsi - fi1) + fabsf(fsj - fj1);
            o.y = v.y * (TAU * fmaxf(fmaf(d, nC, 1.0f), -1.0f));
        }
        {
            const float d = fabsf(fsi - fi2) + fabsf(fsj - fj2);
            o.z = v.z * (TAU * fmaxf(fmaf(d, nC, 1.0f), -1.0f));
        }
        {
            const float d = fabsf(fsi - fi3) + fabsf(fsj - fj3);
            o.w = v.w * (TAU * fmaxf(fmaf(d, nC, 1.0f), -1.0f));
        }
        *(f32x4*)(po + (size_t)k * DEPTH) = o;
    }
}

extern "C" void kernel_launch(void* const* d_in, const int* in_sizes, int n_in,
                              void* d_out, int out_size, void* d_ws, size_t ws_size,
                              hipStream_t stream) {
    (void)in_sizes; (void)n_in; (void)out_size; (void)d_ws; (void)ws_size;
    const float* x = (const float*)d_in[0];
    float* out = (float*)d_out;
    dim3 grid(NB * (DEPTH / CTILE));  // 4096
    dim3 block(BLK);
    hipLaunchKernelGGL(mask_kernel, grid, block, 0, stream, x, out);
}

// Round 10
// 91.606 us; speedup vs baseline: 1.6821x; 1.0942x over previous
//
#include <hip/hip_runtime.h>
#include <math.h>

// Problem constants (from the JAX reference)
#define IMG    14
#define HW     196       // 14*14 spatial positions
#define DEPTH  512       // channels C
#define NB     512       // batch
#define RPT    14        // spatial positions per thread (one full image row pair? no: 196/14)
#define NGRP   32        // f32x4 channel groups per block tile (128 ch)
#define CTILE  128       // channels per block
#define NWAVE  7
#define BLK    448

typedef float f32x4 __attribute__((ext_vector_type(4)));
typedef int   i32x4 __attribute__((ext_vector_type(4)));

// Block: 448 threads = 7 waves, CTILE=128 channels (R3's geometry -- the best
// L3-retaining variant), dwordx4 everywhere. Thread (g = tid&31: f32x4 group,
// q = tid>>5: 14 consecutive positions s = 14q+k) -> si = q, sj = k EXACTLY
// (no div/mod in the whole kernel). Argmax: strict-> thread scan (ascending),
// one shfl_xor(32) merge (lanes l, l^32 share g), 7-wave LDS partial merge
// with idx-min tie-break == jnp.argmax first-occurrence.
// KEY CHANGE vs R9: output stored with __builtin_nontemporal_store (nt flag,
// no cache allocation) so the 196 MB output stream does NOT evict the 196 MB
// input from the 256 MB L3 -> input stays L3-resident across graph replays ->
// steady-state FETCH ~0 and phase-2 re-reads are L3 hits; kernel becomes
// write-bound. Grid: 512 b x 4 ctiles = 2048 blocks.
__global__ __launch_bounds__(BLK) void mask_kernel(const float* __restrict__ x,
                                                   float* __restrict__ out) {
    const int tid = threadIdx.x;
    const int g   = tid & 31;      // channel group within 128-ch tile
    const int q   = tid >> 5;      // spatial segment 0..13 (si = q)
    const int w   = tid >> 6;      // wave 0..6
    const int b   = blockIdx.x >> 2;
    const int ct  = blockIdx.x & 3;
    const int c0  = ct * CTILE + (g << 2);

    const size_t base = ((size_t)b * HW + (size_t)q * RPT) * DEPTH + (size_t)c0;
    const float* px = x + base;
    float*       po = out + base;

    // ---- Phase 1: 14 dwordx4 loads, streaming per-component argmax ----
    float b0 = -INFINITY, b1 = -INFINITY, b2 = -INFINITY, b3 = -INFINITY;
    int   i0 = 0, i1 = 0, i2 = 0, i3 = 0;
#pragma unroll
    for (int k = 0; k < RPT; ++k) {
        const f32x4 v = *(const f32x4*)(px + (size_t)k * DEPTH);
        const int s = q * RPT + k;   // ascending: strict > = first occurrence
        if (v.x > b0) { b0 = v.x; i0 = s; }
        if (v.y > b1) { b1 = v.y; i1 = s; }
        if (v.z > b2) { b2 = v.z; i2 = s; }
        if (v.w > b3) { b3 = v.w; i3 = s; }
    }

    // ---- Intra-wave merge: lanes l and l^32 share g (q = 2w, 2w+1) ----
    // (val >, or == with smaller idx) == first occurrence, any merge order.
    {
        const float o0 = __shfl_xor(b0, 32); const int oi0 = __shfl_xor(i0, 32);
        const float o1 = __shfl_xor(b1, 32); const int oi1 = __shfl_xor(i1, 32);
        const float o2 = __shfl_xor(b2, 32); const int oi2 = __shfl_xor(i2, 32);
        const float o3 = __shfl_xor(b3, 32); const int oi3 = __shfl_xor(i3, 32);
        if (o0 > b0 || (o0 == b0 && oi0 < i0)) { b0 = o0; i0 = oi0; }
        if (o1 > b1 || (o1 == b1 && oi1 < i1)) { b1 = o1; i1 = oi1; }
        if (o2 > b2 || (o2 == b2 && oi2 < i2)) { b2 = o2; i2 = oi2; }
        if (o3 > b3 || (o3 == b3 && oi3 < i3)) { b3 = o3; i3 = oi3; }
    }

    // ---- Cross-wave merge via LDS partials (7 KB) ----
    __shared__ f32x4 pmax[NWAVE][NGRP];
    __shared__ i32x4 pidx[NWAVE][NGRP];
    if ((tid & 63) < 32) {
        pmax[w][g] = (f32x4){b0, b1, b2, b3};
        pidx[w][g] = (i32x4){i0, i1, i2, i3};
    }
    __syncthreads();

    f32x4 mv = pmax[0][g];
    i32x4 mi = pidx[0][g];
#pragma unroll
    for (int r = 1; r < NWAVE; ++r) {
        const f32x4 vv = pmax[r][g];
        const i32x4 ii = pidx[r][g];
        if (vv.x > mv.x || (vv.x == mv.x && ii.x < mi.x)) { mv.x = vv.x; mi.x = ii.x; }
        if (vv.y > mv.y || (vv.y == mv.y && ii.y < mi.y)) { mv.y = vv.y; mi.y = ii.y; }
        if (vv.z > mv.z || (vv.z == mv.z && ii.z < mi.z)) { mv.z = vv.z; mi.z = ii.z; }
        if (vv.w > mv.w || (vv.w == mv.w && ii.w < mi.w)) { mv.w = vv.w; mi.w = ii.w; }
    }

    const float fi0 = (float)(mi.x / IMG), fj0 = (float)(mi.x % IMG);
    const float fi1 = (float)(mi.y / IMG), fj1 = (float)(mi.y % IMG);
    const float fi2 = (float)(mi.z / IMG), fj2 = (float)(mi.z % IMG);
    const float fi3 = (float)(mi.w / IMG), fj3 = (float)(mi.w % IMG);
    const float TAU = (float)(0.5 / 196.0);
    const float nC  = -(float)(4.0 / 14.0);   // fma replaces the fp32 divide

    const float fsi = (float)q;   // s = 14q + k  =>  si = q (exact)

    // ---- Phase 2: re-read (L3-hot), division-free mask, NT store ----
#pragma unroll
    for (int k = 0; k < RPT; ++k) {
        const f32x4 v = *(const f32x4*)(px + (size_t)k * DEPTH);
        const float fsj = (float)k;          // sj = k (exact, compile-time)
        f32x4 o;
        {
            const float d = fabsf(fsi - fi0) + fabsf(fsj - fj0);
            o.x = v.x * (TAU * fmaxf(fmaf(d, nC, 1.0f), -1.0f));
        }
        {
            const float d = fabsf(fsi - fi1) + fabsf(fsj - fj1);
            o.y = v.y * (TAU * fmaxf(fmaf(d, nC, 1.0f), -1.0f));
        }
        {
            const float d = fabsf(fsi - fi2) + fabsf(fsj - fj2);
            o.z = v.z * (TAU * fmaxf(fmaf(d, nC, 1.0f), -1.0f));
        }
        {
            const float d = fabsf(fsi - fi3) + fabsf(fsj - fj3);
            o.w = v.w * (TAU * fmaxf(fmaf(d, nC, 1.0f), -1.0f));
        }
        __builtin_nontemporal_store(o, (f32x4*)(po + (size_t)k * DEPTH));
    }
}

extern "C" void kernel_launch(void* const* d_in, const int* in_sizes, int n_in,
                              void* d_out, int out_size, void* d_ws, size_t ws_size,
                              hipStream_t stream) {
    (void)in_sizes; (void)n_in; (void)out_size; (void)d_ws; (void)ws_size;
    const float* x = (const float*)d_in[0];
    float* out = (float*)d_out;
    dim3 grid(NB * (DEPTH / CTILE));  // 2048
    dim3 block(BLK);
    hipLaunchKernelGGL(mask_kernel, grid, block, 0, stream, x, out);
}

// Round 11
// 85.871 us; speedup vs baseline: 1.7944x; 1.0668x over previous
//
#include <hip/hip_runtime.h>
#include <math.h>

// Problem constants (from the JAX reference)
#define IMG    14
#define HW     196       // 14*14 spatial positions
#define DEPTH  512       // channels C
#define NB     512       // batch
#define NSEG   7         // waves per block = spatial segments
#define PS     28        // spatial positions per wave (196 / 7)
#define CTILE  128       // channels per block (64 lanes x f32x2)

typedef float f32x2 __attribute__((ext_vector_type(2)));

// R11 = R3 (best measured: 83.3 us) with exactly two surgical changes:
//  (1) mask uses fmaf(dist, -4/14, 1) instead of the fp32 division
//      (4*dist)/14.0f -- kills the ~9-inst v_div sequence x2 components
//      x28 iters per thread (~500 VALU insts/thread in the epilogue).
//  (2) float coords of the (si,sj) walk kept as floats incrementally
//      (no per-iter int->float converts).
// Everything else identical to R3: dwordx2 loads, 448 threads = 7 waves,
// CTILE=128, asm-pinned register values (eager loads, deep vmcnt pipeline),
// LDS partial argmax merge, 2048 blocks.
__global__ __launch_bounds__(448) void mask_kernel(const float* __restrict__ x,
                                                   float* __restrict__ out) {
    const int tid  = threadIdx.x;
    const int lane = tid & 63;
    const int q    = tid >> 6;          // 0..6, spatial segment == wave id
    const int b    = blockIdx.x >> 2;
    const int ct   = blockIdx.x & 3;
    const int c0   = ct * CTILE + (lane << 1);   // first of this lane's 2 channels

    // base float offset of (b, s = q*28, c0)
    const size_t base = ((size_t)b * HW + (size_t)q * PS) * DEPTH + (size_t)c0;
    const float* px = x + base;
    float*       po = out + base;

    // ---- Phase 1: load 28 f32x2 into registers (56 VGPRs, all in flight) ----
    f32x2 v[PS];
#pragma unroll
    for (int k = 0; k < PS; ++k) {
        v[k] = *(const f32x2*)(px + (size_t)k * DEPTH);
    }

    // per-component streaming argmax (first occurrence: strict >)
    float b0 = -INFINITY, b1 = -INFINITY;
    int   i0 = 0, i1 = 0;
#pragma unroll
    for (int k = 0; k < PS; ++k) {
        const int s = q * PS + k;
        if (v[k].x > b0) { b0 = v[k].x; i0 = s; }
        if (v[k].y > b1) { b1 = v[k].y; i1 = s; }
    }

    // ---- Pin loaded values in registers: make them opaque so the compiler
    // cannot rematerialize the global loads in the store phase ----
#pragma unroll
    for (int k = 0; k < PS; ++k) {
        float a = v[k].x, c = v[k].y;
        asm volatile("" : "+v"(a), "+v"(c));
        v[k].x = a; v[k].y = c;
    }

    // ---- Cross-segment reduction via LDS ----
    __shared__ f32x2 smax[NSEG][64];
    __shared__ int   sidx[NSEG][64][2];
    f32x2 bv; bv.x = b0; bv.y = b1;
    smax[q][lane] = bv;
    sidx[q][lane][0] = i0; sidx[q][lane][1] = i1;
    __syncthreads();

    f32x2 m = smax[0][lane];
    int mi0 = sidx[0][lane][0], mi1 = sidx[0][lane][1];
#pragma unroll
    for (int r = 1; r < NSEG; ++r) {
        // segments scanned in increasing spatial order; strict > keeps the
        // first occurrence, matching jnp.argmax tie semantics
        const f32x2 vv = smax[r][lane];
        if (vv.x > m.x) { m.x = vv.x; mi0 = sidx[r][lane][0]; }
        if (vv.y > m.y) { m.y = vv.y; mi1 = sidx[r][lane][1]; }
    }

    const float fi0 = (float)(mi0 / IMG), fj0 = (float)(mi0 % IMG);
    const float fi1 = (float)(mi1 / IMG), fj1 = (float)(mi1 % IMG);
    const float TAU = (float)(0.5 / 196.0);
    const float nC  = -(float)(4.0 / 14.0);   // fma replaces the fp32 divide

    // ---- Phase 2: mask register-held values, store (no global re-read) ----
    float fsi = (float)((q * PS) / IMG);
    float fsj = (float)((q * PS) % IMG);
    int   sj  = (q * PS) % IMG;
#pragma unroll
    for (int k = 0; k < PS; ++k) {
        f32x2 o;
        {
            const float d = fabsf(fsi - fi0) + fabsf(fsj - fj0);
            o.x = v[k].x * (TAU * fmaxf(fmaf(d, nC, 1.0f), -1.0f));
        }
        {
            const float d = fabsf(fsi - fi1) + fabsf(fsj - fj1);
            o.y = v[k].y * (TAU * fmaxf(fmaf(d, nC, 1.0f), -1.0f));
        }
        *(f32x2*)(po + (size_t)k * DEPTH) = o;
        ++sj; fsj += 1.0f;
        if (sj == IMG) { sj = 0; fsj = 0.0f; fsi += 1.0f; }
    }
}

extern "C" void kernel_launch(void* const* d_in, const int* in_sizes, int n_in,
                              void* d_out, int out_size, void* d_ws, size_t ws_size,
                              hipStream_t stream) {
    (void)in_sizes; (void)n_in; (void)out_size; (void)d_ws; (void)ws_size;
    const float* x = (const float*)d_in[0];
    float* out = (float*)d_out;
    dim3 grid(NB * (DEPTH / CTILE));  // 2048
    dim3 block(448);
    hipLaunchKernelGGL(mask_kernel, grid, block, 0, stream, x, out);
}